// Round 8
// baseline (518.171 us; speedup 1.0000x reference)
//
#include <hip/hip_runtime.h>
#include <hip/hip_bf16.h>

// MultiHeadSelfAttention: B=4, S=1024, D=512(d_model = per-head dim), H=8
// out  = [B*S, D]    fp32 at d_out
// attn = [H*B, S, S] fp32 at d_out + B*S*D
//
// All GEMMs are BT (B given as [N][K] bf16, k-contiguous).
// V is computed directly transposed (vT[hb][d][s]) via a row-bias GEMM.
//
// This round: step-5 (AF32) staging converted to T14 async-split reg-staging:
// issue tile-(t+1) global loads (A fp32 x4, B bf16 x2 per thread) right after
// tile-t's ds_writes, so HBM latency hides under compute(t). A's XOR swizzle
// moves to the ds_write address (same involution as the reads); global reads
// are now linear. LDS stays 24KB; VGPR +24 (<=128 cap, 4 blocks/CU holds).
// Everything else identical to round-7 (479.6 us).
//
// d_ws layout (87.1 MB <= 100.7 MB proven available):
//   xb   bf16 [4096,512]    4 MB
//   WqT  bf16 [4096,512]    4 MB
//   WkT  bf16 [4096,512]    4 MB   (contiguous after WqT -> stacked B)
//   WvT  bf16 [4096,512]    4 MB
//   WoT  bf16 [512,4096]    4 MB
//   buf1 bf16 [4096,4096]  33.5 MB   (q  -> vT)
//   buf2 bf16 [4096,4096]  33.5 MB   (k  -> ctx)

typedef unsigned short u16;
typedef __attribute__((ext_vector_type(8))) short short8;
typedef __attribute__((ext_vector_type(4))) float f32x4;
typedef __attribute__((ext_vector_type(2))) unsigned int u32x2;

#define BK 32

__device__ __forceinline__ u16 f2bf(float f) {
    union { float f; unsigned u; } v; v.f = f;
    unsigned u = v.u;
    u += 0x7fffu + ((u >> 16) & 1u);   // round-to-nearest-even
    return (u16)(u >> 16);
}

__device__ __forceinline__ void gl2lds16(const void* g, void* l) {
    __builtin_amdgcn_global_load_lds(
        (const __attribute__((address_space(1))) void*)g,
        (__attribute__((address_space(3))) void*)l, 16, 0, 0);
}

// C = scale * (A @ B^T) + bias.  A:[M,K] (fp32 or bf16), B:[N,K] bf16.
// Tile: BM=MF*32 x BN=NF*32, 4 waves in 2x2, BK=32, 16x16x32 bf16 MFMA.
// Batch via (swizzled) blockIdx.z: zh = z/nb, zb = z%nb.
// AF32 (!PIPE): T14 reg-staged single-buffer loop; A fp32 in LDS with
//       ds_write-side XOR swizzle, cvt_pk to bf16 at fragment load.
// PIPE: 3-buffer counted-vmcnt pipeline (bf16-A only).
// DUALN: B is two stacked weight matrices; columns n>=nsplit write to
//        Cp2 with bias2 (block-uniform select; n0 is a multiple of BN).
template<int MF, int NF, bool AF32, bool OUTF32, bool ROWBIAS, bool PIPE, bool DUALN>
__global__ __launch_bounds__(256, 4)
void gemm_bt(const void* __restrict__ Ap, int lda, long long sAh, long long sAb,
             const u16* __restrict__ Bp, int ldb, long long sBh, long long sBb,
             void* __restrict__ Cp, int ldc, long long sCh, long long sCb,
             int K, const float* __restrict__ bias, long long sbias,
             float scale, int nb,
             int nsplit, void* __restrict__ Cp2, const float* __restrict__ bias2)
{
    static_assert(!(PIPE && AF32), "PIPE path assumes bf16 A staging");
    constexpr int BMt = MF * 32, BNt = NF * 32;
    constexpr int AW = AF32 ? 2 * BK : BK;   // A row width in u16
    constexpr int NBUF = PIPE ? 3 : 1;
    constexpr int LPT = BMt / 64 + BNt / 64; // gl2lds per thread per stage (bf16)
    __shared__ __attribute__((aligned(16))) u16 Alds[NBUF][BMt][AW];
    __shared__ __attribute__((aligned(16))) u16 Blds[NBUF][BNt][BK];

    // T1: bijective XCD-aware remap of the flattened workgroup id (m204).
    int bx = blockIdx.x, by = blockIdx.y, bz = blockIdx.z;
    {
        const int gx = gridDim.x, gy = gridDim.y;
        const int nwg = gx * gy * (int)gridDim.z;
        const int wgid = bx + gx * (by + gy * bz);
        const int xcd = wgid & 7, lp = wgid >> 3;
        const int q = nwg >> 3, r = nwg & 7;
        int nid = (xcd < r ? xcd * (q + 1) : r * (q + 1) + (xcd - r) * q) + lp;
        bx = nid % gx; nid /= gx; by = nid % gy; bz = nid / gy;
    }

    const int zh = bz / nb, zb = bz % nb;
    const int m0 = by * BMt;
    const int n0 = bx * BNt;     // global n (indexes B rows)

    const int tid  = threadIdx.x;
    const int lane = tid & 63;
    const int wave = tid >> 6;
    const int wm = (wave >> 1) * (MF * 16);
    const int wn = (wave & 1) * (NF * 16);

    const float* Afp = (const float*)Ap + (long long)zh * sAh + (long long)zb * sAb;
    const u16*   Abf = (const u16*)Ap + (long long)zh * sAh + (long long)zb * sAb;
    const u16*   Bbf = Bp + (long long)zh * sBh + (long long)zb * sBb;

    // DUALN: route output half (block-uniform since n0 % BNt == 0)
    void* Csel = Cp;
    const float* bsel = bias;
    int nC = n0;
    if (DUALN && n0 >= nsplit) { Csel = Cp2; bsel = bias2; nC = n0 - nsplit; }

    f32x4 acc[MF][NF] = {};

    auto stage = [&](int buf, int kt) {   // bf16 async staging (PIPE / fallback)
        #pragma unroll
        for (int i = 0; i < BMt / 64; ++i) {
            int idx = i * 256 + tid;
            int row = idx >> 2;
            int kq  = (idx & 3) << 3;
            gl2lds16(Abf + (long long)(m0 + row) * lda + (kt + kq),
                     &Alds[buf][row][kq]);
        }
        #pragma unroll
        for (int i = 0; i < BNt / 64; ++i) {
            int idx = i * 256 + tid;
            int row = idx >> 2;
            int kq  = (idx & 3) << 3;
            gl2lds16(Bbf + (long long)(n0 + row) * ldb + (kt + kq),
                     &Blds[buf][row][kq]);
        }
    };

    auto compute = [&](int buf) {
        const int kq = (lane >> 4) << 3;
        const int fr = lane & 15;
        short8 af[MF], bfr[NF];
        if (AF32) {
            const int c0 = (lane >> 4) << 1;   // first 16B chunk of my k-slice
            #pragma unroll
            for (int im = 0; im < MF; ++im) {
                int row = wm + im * 16 + fr;
                int s   = row & 7;
                const float* ar = (const float*)&Alds[buf][row][0];
                f32x4 lo = *(const f32x4*)(ar + (((c0    ) ^ s) << 2));
                f32x4 hi = *(const f32x4*)(ar + (((c0 + 1) ^ s) << 2));
                union { short8 v; __hip_bfloat162 h[4]; } a;
                a.h[0] = __float22bfloat162_rn(make_float2(lo.x, lo.y));
                a.h[1] = __float22bfloat162_rn(make_float2(lo.z, lo.w));
                a.h[2] = __float22bfloat162_rn(make_float2(hi.x, hi.y));
                a.h[3] = __float22bfloat162_rn(make_float2(hi.z, hi.w));
                af[im] = a.v;
            }
        } else {
            #pragma unroll
            for (int im = 0; im < MF; ++im)
                af[im] = *(const short8*)(&Alds[buf][wm + im * 16 + fr][kq]);
        }
        #pragma unroll
        for (int in = 0; in < NF; ++in)
            bfr[in] = *(const short8*)(&Blds[buf][wn + in * 16 + fr][kq]);
        #pragma unroll
        for (int im = 0; im < MF; ++im)
            #pragma unroll
            for (int in = 0; in < NF; ++in)
                acc[im][in] = __builtin_amdgcn_mfma_f32_16x16x32_bf16(
                    af[im], bfr[in], acc[im][in], 0, 0, 0);
    };

    const int nt = K / BK;
    if (PIPE) {
        // 3-buffer counted-vmcnt pipeline. Invariant at top of iter t:
        // tiles t (LPT loads) and t+1 (LPT) outstanding per wave.
        // vmcnt(LPT) retires tile t (oldest-first); raw barrier then proves
        // all waves' tile-t loads landed. stage(t+2) goes AFTER the barrier
        // because buffer (t+2)%3 == (t-1)%3 was read in compute(t-1).
        stage(0, 0);
        stage(1, BK);
        for (int t = 0; t < nt; ++t) {
            if (t < nt - 1) {
                if constexpr (LPT == 4)
                    asm volatile("s_waitcnt vmcnt(4)" ::: "memory");
                else if constexpr (LPT == 3)
                    asm volatile("s_waitcnt vmcnt(3)" ::: "memory");
                else if constexpr (LPT == 2)
                    asm volatile("s_waitcnt vmcnt(2)" ::: "memory");
                else
                    asm volatile("s_waitcnt vmcnt(0)" ::: "memory");
            } else {
                asm volatile("s_waitcnt vmcnt(0)" ::: "memory");
            }
            __builtin_amdgcn_s_barrier();
            __builtin_amdgcn_sched_barrier(0);
            const int nx = t + 2;
            if (nx < nt) stage(nx - nx / 3 * 3, nx * BK);
            compute(t - t / 3 * 3);
        }
        __builtin_amdgcn_s_barrier();   // all reads done before block exits
    } else if (AF32) {
        // T14 async-split reg-staged single-buffer loop.
        // Regs for tile t+1 are loaded while compute(t) runs; the implicit
        // vmcnt wait (compiler, at the ds_write use) lands after a full
        // compute phase of latency cover.
        f32x4 pa[BMt / 32];          // A: 4 x 16B fp32 chunks per thread
        f32x4 pb[BNt / 64];          // B: 2 x 16B bf16 chunks per thread
        auto load_regs = [&](int kt) {
            #pragma unroll
            for (int i = 0; i < BMt / 32; ++i) {
                int idx = i * 256 + tid, row = idx >> 3, c = idx & 7;
                pa[i] = *(const f32x4*)(Afp + (long long)(m0 + row) * lda
                                        + kt + (c << 2));    // linear read
            }
            #pragma unroll
            for (int i = 0; i < BNt / 64; ++i) {
                int idx = i * 256 + tid, row = idx >> 2, kq = (idx & 3) << 3;
                pb[i] = *(const f32x4*)(Bbf + (long long)(n0 + row) * ldb
                                        + (kt + kq));
            }
        };
        auto write_lds = [&]() {
            #pragma unroll
            for (int i = 0; i < BMt / 32; ++i) {
                int idx = i * 256 + tid, row = idx >> 3, c = idx & 7;
                // swizzle on the WRITE address: LDS chunk c^(row&7) holds
                // global chunk c  ->  LDS chunk c' holds global c'^s, the
                // exact content the compute-side (c0^s) reads expect.
                *(f32x4*)(&Alds[0][row][(c ^ (row & 7)) << 3]) = pa[i];
            }
            #pragma unroll
            for (int i = 0; i < BNt / 64; ++i) {
                int idx = i * 256 + tid, row = idx >> 2, kq = (idx & 3) << 3;
                *(f32x4*)(&Blds[0][row][kq]) = pb[i];
            }
        };
        load_regs(0);
        for (int t = 0; t < nt; ++t) {
            __syncthreads();             // all waves done reading LDS (t>0)
            write_lds();                 // waits pa/pb via register dep
            if (t + 1 < nt) load_regs((t + 1) * BK);  // fly during compute
            __syncthreads();             // writes visible
            compute(0);
        }
    } else {
        for (int t = 0; t < nt; ++t) {
            __syncthreads();
            stage(0, t * BK);
            __syncthreads();
            compute(0);
        }
    }

    // ---- epilogue: C[row=(lane>>4)*4+r][col=lane&15] ----
    float* Cfp = (float*)Csel + (long long)zh * sCh + (long long)zb * sCb;
    u16*   Cbf = (u16*)Csel + (long long)zh * sCh + (long long)zb * sCb;
    const float* biasp = bsel ? bsel + (long long)zh * sbias : nullptr;
    const int rb  = (lane >> 4) << 2;
    const int col = lane & 15;
    #pragma unroll
    for (int im = 0; im < MF; ++im) {
        #pragma unroll
        for (int r = 0; r < 4; ++r) {
            int row = m0 + wm + im * 16 + rb + r;
            float rbias = (biasp && ROWBIAS) ? biasp[row] : 0.0f;
            #pragma unroll
            for (int in = 0; in < NF; ++in) {
                int cc = nC + wn + in * 16 + col;
                float v = acc[im][in][r] * scale;
                if (biasp) v += ROWBIAS ? rbias : biasp[cc];
                if (OUTF32) Cfp[(long long)row * ldc + cc] = v;
                else        Cbf[(long long)row * ldc + cc] = f2bf(v);
            }
        }
    }
}

// In-place softmax over rows of 1024 fp32. One 256-thread block per row.
__global__ __launch_bounds__(256)
void softmax_kernel(float* __restrict__ attn)
{
    const long long row = blockIdx.x;
    float* p = attn + row * 1024;
    const int tid  = threadIdx.x;
    const int lane = tid & 63;
    const int wave = tid >> 6;
    __shared__ float red[8];

    f32x4 v = *(f32x4*)(p + tid * 4);
    float mx = fmaxf(fmaxf(v.x, v.y), fmaxf(v.z, v.w));
    #pragma unroll
    for (int off = 1; off < 64; off <<= 1)
        mx = fmaxf(mx, __shfl_xor(mx, off, 64));
    if (lane == 0) red[wave] = mx;
    __syncthreads();
    mx = fmaxf(fmaxf(red[0], red[1]), fmaxf(red[2], red[3]));

    v.x = __expf(v.x - mx);
    v.y = __expf(v.y - mx);
    v.z = __expf(v.z - mx);
    v.w = __expf(v.w - mx);
    float s = v.x + v.y + v.z + v.w;
    #pragma unroll
    for (int off = 1; off < 64; off <<= 1)
        s += __shfl_xor(s, off, 64);
    if (lane == 0) red[4 + wave] = s;
    __syncthreads();
    s = red[4] + red[5] + red[6] + red[7];
    float inv = 1.0f / s;
    v.x *= inv; v.y *= inv; v.z *= inv; v.w *= inv;
    *(f32x4*)(p + tid * 4) = v;
}

// x fp32 -> bf16 elementwise
__global__ __launch_bounds__(256)
void cvt_kernel(const float* __restrict__ in, u16* __restrict__ out)
{
    long long i = (long long)blockIdx.x * 256 + threadIdx.x;
    f32x4 v = *(const f32x4*)(in + i * 4);
    u32x2 p;
    p.x = (unsigned)f2bf(v.x) | ((unsigned)f2bf(v.y) << 16);
    p.y = (unsigned)f2bf(v.z) | ((unsigned)f2bf(v.w) << 16);
    *(u32x2*)(out + i * 4) = p;
}

// transpose fp32 [R][C] -> bf16 [C][R]; 64x64 tiles, grid (C/64, R/64)
__global__ __launch_bounds__(256)
void wtrans_kernel(const float* __restrict__ in, u16* __restrict__ out, int R, int C)
{
    __shared__ __attribute__((aligned(16))) u16 t[64][72];
    const int r0 = blockIdx.y * 64, c0 = blockIdx.x * 64;
    const int tid = threadIdx.x;
    const int lr = tid >> 4;
    const int lc = (tid & 15) << 2;
    #pragma unroll
    for (int j = 0; j < 4; ++j) {
        int rr = lr + j * 16;
        f32x4 v = *(const f32x4*)(in + (long long)(r0 + rr) * C + c0 + lc);
        u32x2 p;
        p.x = (unsigned)f2bf(v.x) | ((unsigned)f2bf(v.y) << 16);
        p.y = (unsigned)f2bf(v.z) | ((unsigned)f2bf(v.w) << 16);
        *(u32x2*)(&t[rr][lc]) = p;
    }
    __syncthreads();
    const int oc = tid >> 2;
    const int rs = (tid & 3) << 4;
    union { short8 v; u16 e[8]; } a, b;
    #pragma unroll
    for (int j = 0; j < 8; ++j) a.e[j] = t[rs + j][oc];
    #pragma unroll
    for (int j = 0; j < 8; ++j) b.e[j] = t[rs + 8 + j][oc];
    u16* o = out + (long long)(c0 + oc) * R + r0 + rs;
    *(short8*)o = a.v;
    *(short8*)(o + 8) = b.v;
}

extern "C" void kernel_launch(void* const* d_in, const int* in_sizes, int n_in,
                              void* d_out, int out_size, void* d_ws, size_t ws_size,
                              hipStream_t stream)
{
    const float* x  = (const float*)d_in[0];
    const float* Wq = (const float*)d_in[1];
    const float* bq = (const float*)d_in[2];
    const float* Wk = (const float*)d_in[3];
    const float* bk = (const float*)d_in[4];
    const float* Wv = (const float*)d_in[5];
    const float* bv = (const float*)d_in[6];
    const float* Wo = (const float*)d_in[7];
    const float* bo = (const float*)d_in[8];

    const int B = 4, S = 1024, D = 512, H = 8;
    const int HD = H * D;   // 4096
    const int BS = B * S;   // 4096

    float* out  = (float*)d_out;                     // [4096, 512]
    float* attn = out + (long long)BS * D;           // [32, 1024, 1024]

    u16* xb   = (u16*)d_ws;                          // [4096,512]
    u16* WqT  = xb  + (long long)BS * D;
    u16* WkT  = WqT + (long long)HD * D;             // contiguous after WqT
    u16* WvT  = WkT + (long long)HD * D;
    u16* WoT  = WvT + (long long)HD * D;             // [512,4096]
    u16* buf1 = WoT + (long long)D * HD;             // [4096,4096]
    u16* buf2 = buf1 + (long long)BS * HD;

    dim3 blk(256);

    // 0) prep: x -> bf16, weights -> transposed bf16
    cvt_kernel<<<dim3(BS * D / 1024), blk, 0, stream>>>(x, xb);
    wtrans_kernel<<<dim3(HD / 64, D / 64), blk, 0, stream>>>(Wq, WqT, D, HD);
    wtrans_kernel<<<dim3(HD / 64, D / 64), blk, 0, stream>>>(Wk, WkT, D, HD);
    wtrans_kernel<<<dim3(HD / 64, D / 64), blk, 0, stream>>>(Wv, WvT, D, HD);
    wtrans_kernel<<<dim3(D / 64, HD / 64), blk, 0, stream>>>(Wo, WoT, HD, D);

    // 1) fused q,k = xb @ [WqT;WkT]^T -> buf1 / buf2   [128x128 tiles, 2048 blks]
    {
        dim3 g(2 * HD / 128, BS / 128, 1);
        gemm_bt<4,4,false,false,false,true,true><<<g, blk, 0, stream>>>(
            xb, D, 0, 0, WqT, D, 0, 0, buf1, HD, 0, 0, D, bq, 0, 1.0f, 1,
            HD, buf2, bk);
    }
    // 2) scores = q @ k^T / 512 per (h,b) -> fp32 attn region
    {
        dim3 g(S / 128, S / 128, H * B);
        gemm_bt<4,4,false,true,false,true,false><<<g, blk, 0, stream>>>(
            buf1, HD, D, (long long)S * HD,
            buf2, HD, D, (long long)S * HD,
            attn, S, (long long)B * S * S, (long long)S * S,
            D, nullptr, 0, 1.0f / (float)D, B,
            1 << 30, nullptr, nullptr);
    }
    // 3) row softmax in place
    softmax_kernel<<<dim3(H * B * S), blk, 0, stream>>>(attn);
    // 4) vT[hb][d][s] = Wv^T slice @ xb^T + bv  -> buf1 (q dead); row bias
    {
        dim3 g(S / 128, D / 128, H * B);
        gemm_bt<4,4,false,false,true,true,false><<<g, blk, 0, stream>>>(
            WvT, D, (long long)D * D, 0,
            xb, D, 0, (long long)S * D,
            buf1, S, (long long)B * D * S, (long long)D * S,
            D, bv, D, 1.0f, B,
            1 << 30, nullptr, nullptr);
    }
    // 5) ctx = attn @ vT^T per (h,b) -> buf2 bf16 (k dead)   [128x128 tiles]
    //    T14 reg-staged async-split; ds_write-side XOR swizzle; 1024 blocks.
    {
        dim3 g(D / 128, S / 128, H * B);
        gemm_bt<4,4,true,false,false,false,false><<<g, blk, 0, stream>>>(
            attn, S, (long long)B * S * S, (long long)S * S,
            buf1, S, (long long)B * D * S, (long long)D * S,
            buf2, HD, D, (long long)S * HD,
            S, nullptr, 0, 1.0f, B,
            1 << 30, nullptr, nullptr);
    }
    // 6) out = ctx @ WoT^T + bo -> fp32   [64x64 tiles, 512 blocks]
    {
        dim3 g(D / 64, BS / 64, 1);
        gemm_bt<2,2,false,true,false,true,false><<<g, blk, 0, stream>>>(
            buf2, HD, 0, 0, WoT, HD, 0, 0, out, D, 0, 0, HD, bo, 0, 1.0f, 1,
            1 << 30, nullptr, nullptr);
    }
}